// Round 9
// baseline (393.270 us; speedup 1.0000x reference)
//
#include <hip/hip_runtime.h>
#include <cstddef>

// GGNN: B=8, V=1536, H=64, E=4, T=5 (constants from setup_inputs()).
constexpr int Bn = 8, Vn = 1536, Hn = 64, En = 4, Tn = 5;
constexpr int CAP = 64;              // max nnz per adjacency row (mean 15.4, >12 sigma)
constexpr int NROWS = Bn * En * Vn;  // 49152
constexpr int PADROW = Bn * Vn;      // 12288 -> zeroed pad row in hA/hB
constexpr int NT = 16;               // nodes per wave (MFMA M=16)

typedef float fx4 __attribute__((ext_vector_type(4)));
typedef float f32x4 __attribute__((ext_vector_type(4)));
typedef short bf16x8 __attribute__((ext_vector_type(8)));

__device__ __forceinline__ unsigned short f2bf(float x) {
  unsigned u = __float_as_uint(x);
  return (unsigned short)((u + 0x7fffu + ((u >> 16) & 1u)) >> 16);
}
__device__ __forceinline__ float bf2f(unsigned short h) {
  return __uint_as_float(((unsigned)h) << 16);
}

// ---------------------------------------------------------------------------
// Pass 1: compact binary adjacency [B,E,V,V] into padded GLOBAL index lists.
// ---------------------------------------------------------------------------
__global__ __launch_bounds__(256) void sparsify_kernel(
    const float* __restrict__ adj, int* __restrict__ idx, int* __restrict__ cnt)
{
  __shared__ int lcnt[4];
  __shared__ int sidx[4][CAP];
  const int wid = threadIdx.x >> 6, lane = threadIdx.x & 63;
  const int row = blockIdx.x * 4 + wid;
  if (lane == 0) lcnt[wid] = 0;
  __syncthreads();
  const int b = row / (En * Vn);
  const fx4* a4 = reinterpret_cast<const fx4*>(adj + (size_t)row * Vn);
  for (int i = lane; i < Vn / 4; i += 64) {
    fx4 v = __builtin_nontemporal_load(&a4[i]);
    int base = i * 4;
    if (v.x != 0.f) { int s = atomicAdd(&lcnt[wid], 1); if (s < CAP) sidx[wid][s] = base + 0; }
    if (v.y != 0.f) { int s = atomicAdd(&lcnt[wid], 1); if (s < CAP) sidx[wid][s] = base + 1; }
    if (v.z != 0.f) { int s = atomicAdd(&lcnt[wid], 1); if (s < CAP) sidx[wid][s] = base + 2; }
    if (v.w != 0.f) { int s = atomicAdd(&lcnt[wid], 1); if (s < CAP) sidx[wid][s] = base + 3; }
  }
  __syncthreads();
  const int n = min(lcnt[wid], CAP);
  idx[(size_t)row * CAP + lane] = (lane < n) ? (b * Vn + sidx[wid][lane]) : PADROW;
  if (lane == 0) cnt[row] = n;
}

// ---------------------------------------------------------------------------
// Prep: h0 -> hA (+ zero pads); pack all weights as split-bf16 MFMA B-tiles.
// Tile order: edge e*2+ks (x4 nt) [0,32) ; gates ks*8+nt [32,64) ; cand ks*4+nt [64,80).
// Per tile per lane l: 8 bf16: B[kbase + 4*(l>>4) + (j&3) + 16*(j>>2)][nt*16 + (l&15)].
// wB[(tile*2+0)*64+l] = hi (4 uints of 2 bf16), wB[(tile*2+1)*64+l] = lo.
// ---------------------------------------------------------------------------
__global__ __launch_bounds__(256) void prep_kernel(
    const float* __restrict__ h0, const float* __restrict__ We,
    const float* __restrict__ Wg, const float* __restrict__ Wc,
    float* __restrict__ hA, float* __restrict__ hB, int4* __restrict__ wB)
{
  const int tid = blockIdx.x * 256 + threadIdx.x;
  const int NH4 = Bn * Vn * Hn / 4;
  if (tid < NH4) reinterpret_cast<float4*>(hA)[tid] = reinterpret_cast<const float4*>(h0)[tid];
  const int p = tid - NH4;
  if (p >= 0 && p < 16)  reinterpret_cast<float4*>(hA + (size_t)PADROW * Hn)[p]      = float4{0.f,0.f,0.f,0.f};
  if (p >= 16 && p < 32) reinterpret_cast<float4*>(hB + (size_t)PADROW * Hn)[p - 16] = float4{0.f,0.f,0.f,0.f};
  const int pk = p - 32;
  if (pk >= 0 && pk < 80 * 64) {
    const int tile = pk >> 6, l = pk & 63;
    const int g = l >> 4, n15 = l & 15;
    float w[8];
    if (tile < 32) {
      const int e = tile >> 3, ks = (tile >> 2) & 1, nt = tile & 3;
      const int col = nt * 16 + n15;
      #pragma unroll
      for (int jj = 0; jj < 4; ++jj) {
        w[jj]     = We[e*Hn*Hn + (ks*32      + 4*g + jj)*Hn + col];
        w[4 + jj] = We[e*Hn*Hn + (ks*32 + 16 + 4*g + jj)*Hn + col];
      }
    } else if (tile < 64) {
      const int t2 = tile - 32, ks = t2 >> 3, nt = t2 & 7;
      const int col = nt * 16 + n15;
      #pragma unroll
      for (int jj = 0; jj < 4; ++jj) {
        w[jj]     = Wg[(ks*32      + 4*g + jj)*2*Hn + col];
        w[4 + jj] = Wg[(ks*32 + 16 + 4*g + jj)*2*Hn + col];
      }
    } else {
      const int t2 = tile - 64, ks = t2 >> 2, nt = t2 & 3;
      const int col = nt * 16 + n15;
      #pragma unroll
      for (int jj = 0; jj < 4; ++jj) {
        w[jj]     = Wc[(ks*32      + 4*g + jj)*Hn + col];
        w[4 + jj] = Wc[(ks*32 + 16 + 4*g + jj)*Hn + col];
      }
    }
    unsigned hi[4], lo[4];
    #pragma unroll
    for (int q = 0; q < 4; ++q) {
      unsigned short h0_ = f2bf(w[2*q]), h1_ = f2bf(w[2*q + 1]);
      hi[q] = (unsigned)h0_ | ((unsigned)h1_ << 16);
      unsigned short l0_ = f2bf(w[2*q] - bf2f(h0_)), l1_ = f2bf(w[2*q + 1] - bf2f(h1_));
      lo[q] = (unsigned)l0_ | ((unsigned)l1_ << 16);
    }
    wB[(tile*2 + 0)*64 + l] = int4{(int)hi[0], (int)hi[1], (int)hi[2], (int)hi[3]};
    wB[(tile*2 + 1)*64 + l] = int4{(int)lo[0], (int)lo[1], (int)lo[2], (int)lo[3]};
  }
}

// ---------------------------------------------------------------------------
__device__ __forceinline__ int swzw(int row, int w) {       // word swizzle: chunk ^ row
  return (((w >> 2) ^ (row & 15)) << 2) | (w & 3);
}
__device__ __forceinline__ bf16x8 asbf(int4 v) {
  union { int4 i; bf16x8 b; } u; u.i = v; return u.b;
}
__device__ __forceinline__ void split8(float4 f0, float4 f1, bf16x8& hi, bf16x8& lo) {
  float v[8] = {f0.x, f0.y, f0.z, f0.w, f1.x, f1.y, f1.z, f1.w};
  #pragma unroll
  for (int j = 0; j < 8; ++j) {
    unsigned short h = f2bf(v[j]);
    hi[j] = (short)h;
    lo[j] = (short)f2bf(v[j] - bf2f(h));
  }
}
__device__ __forceinline__ f32x4 mm(bf16x8 a, bf16x8 b, f32x4 c) {
  return __builtin_amdgcn_mfma_f32_16x16x32_bf16(a, b, c, 0, 0, 0);
}

// ---------------------------------------------------------------------------
// Fused step: one wave = 16 nodes. Gather (lane=dim, uniform s_load idx) into
// per-wave LDS (XOR-swizzled); all three matmuls via split-bf16 MFMA; GRU
// nonlinearity elementwise in D-layout. No barriers (per-wave LDS regions).
// ---------------------------------------------------------------------------
__global__ __launch_bounds__(256) void step_kernel(
    const float* __restrict__ hin, float* __restrict__ hout,
    const int* __restrict__ idx, const int* __restrict__ cnt,
    const int4* __restrict__ wB, const float* __restrict__ be,
    const float* __restrict__ bg, const float* __restrict__ bc)
{
  __shared__ float sls[4][En][NT][Hn];   // 64 KB: [wave][e][node][k]; e0->acts, e1->r reuse
  const int lane = threadIdx.x & 63;
  const int wid  = threadIdx.x >> 6;
  const int g = lane >> 4, l15 = lane & 15;
  const int node0 = __builtin_amdgcn_readfirstlane((blockIdx.x * 4 + wid) * NT);
  const int b = node0 / Vn, v0 = node0 - b * Vn;
  const int rbase = b * En * Vn + v0;

  // ---- gather: sls[wid][e][n][d] = sum_{w in row(b,e,v0+n)} hin[w][d] (lane=d)
  for (int n = 0; n < NT; ++n) {
    const int r0 = rbase + n;
    const int c0 = cnt[r0], c1 = cnt[r0 + Vn], c2 = cnt[r0 + 2*Vn], c3 = cnt[r0 + 3*Vn];
    const int4* i0 = reinterpret_cast<const int4*>(idx + (size_t)r0 * CAP);
    const int4* i1 = reinterpret_cast<const int4*>(idx + (size_t)(r0 + Vn) * CAP);
    const int4* i2 = reinterpret_cast<const int4*>(idx + (size_t)(r0 + 2*Vn) * CAP);
    const int4* i3 = reinterpret_cast<const int4*>(idx + (size_t)(r0 + 3*Vn) * CAP);
    const int mr = (max(max(c0, c1), max(c2, c3)) + 3) >> 2;
    float a0 = 0.f, a1 = 0.f, a2 = 0.f, a3 = 0.f;
    for (int j = 0; j < mr; ++j) {
      const int4 w0 = i0[j], w1 = i1[j], w2 = i2[j], w3 = i3[j];   // uniform -> s_load
      a0 += (hin[(size_t)w0.x*Hn + lane] + hin[(size_t)w0.y*Hn + lane])
          + (hin[(size_t)w0.z*Hn + lane] + hin[(size_t)w0.w*Hn + lane]);
      a1 += (hin[(size_t)w1.x*Hn + lane] + hin[(size_t)w1.y*Hn + lane])
          + (hin[(size_t)w1.z*Hn + lane] + hin[(size_t)w1.w*Hn + lane]);
      a2 += (hin[(size_t)w2.x*Hn + lane] + hin[(size_t)w2.y*Hn + lane])
          + (hin[(size_t)w2.z*Hn + lane] + hin[(size_t)w2.w*Hn + lane]);
      a3 += (hin[(size_t)w3.x*Hn + lane] + hin[(size_t)w3.y*Hn + lane])
          + (hin[(size_t)w3.z*Hn + lane] + hin[(size_t)w3.w*Hn + lane]);
    }
    const int sw = swzw(n, lane);
    sls[wid][0][n][sw] = a0;
    sls[wid][1][n][sw] = a1;
    sls[wid][2][n][sw] = a2;
    sls[wid][3][n][sw] = a3;
  }

  // ---- edge transform via MFMA: acts = sum_e s_e @ We[e] + cnt_e*be[e]
  f32x4 acc[4];
  {
    float cv[4][4];                              // [e][j] cnt of node 4g+j
    #pragma unroll
    for (int e = 0; e < 4; ++e)
      #pragma unroll
      for (int j = 0; j < 4; ++j)
        cv[e][j] = (float)cnt[rbase + e*Vn + 4*g + j];
    #pragma unroll
    for (int nt = 0; nt < 4; ++nt) {
      float bev[4];
      #pragma unroll
      for (int e = 0; e < 4; ++e) bev[e] = be[e*Hn + nt*16 + l15];
      #pragma unroll
      for (int j = 0; j < 4; ++j)
        acc[nt][j] = cv[0][j]*bev[0] + cv[1][j]*bev[1] + cv[2][j]*bev[2] + cv[3][j]*bev[3];
    }
  }
  #pragma unroll
  for (int e = 0; e < 4; ++e) {
    const float4* rp4 = reinterpret_cast<const float4*>(&sls[wid][e][l15][0]);
    #pragma unroll
    for (int ks = 0; ks < 2; ++ks) {
      const float4 f0 = rp4[(ks*8 + g) ^ l15];
      const float4 f1 = rp4[(ks*8 + 4 + g) ^ l15];
      bf16x8 ah, al; split8(f0, f1, ah, al);
      #pragma unroll
      for (int nt = 0; nt < 4; ++nt) {
        const int tile = (e*2 + ks)*4 + nt;
        const bf16x8 bh = asbf(wB[(tile*2 + 0)*64 + lane]);
        const bf16x8 bl = asbf(wB[(tile*2 + 1)*64 + lane]);
        acc[nt] = mm(ah, bh, acc[nt]);
        acc[nt] = mm(ah, bl, acc[nt]);
        acc[nt] = mm(al, bh, acc[nt]);
      }
    }
  }

  // ---- repack acts (D-layout) -> LDS [node][k] swizzled (reuse e=0 slice)
  float* actsL = &sls[wid][0][0][0];
  #pragma unroll
  for (int nt = 0; nt < 4; ++nt)
    #pragma unroll
    for (int j = 0; j < 4; ++j) {
      const int m = 4*g + j;
      actsL[m*Hn + swzw(m, nt*16 + l15)] = acc[nt][j];
    }

  // ---- gates via MFMA: gg = [acts, h] @ Wg + bg
  f32x4 gg[8];
  #pragma unroll
  for (int nt = 0; nt < 8; ++nt) {
    const float bgv = bg[nt*16 + l15];
    gg[nt] = (f32x4){bgv, bgv, bgv, bgv};
  }
  bf16x8 aah[2], aal[2];        // acts A-frags kept for cand
  float  hfv[2][8];             // h fp32 kept for rh
  #pragma unroll
  for (int ks = 0; ks < 4; ++ks) {
    bf16x8 ah, al;
    if (ks < 2) {
      const float4* ap4 = reinterpret_cast<const float4*>(&actsL[l15*Hn]);
      const float4 f0 = ap4[(ks*8 + g) ^ l15];
      const float4 f1 = ap4[(ks*8 + 4 + g) ^ l15];
      split8(f0, f1, ah, al);
      aah[ks] = ah; aal[ks] = al;
    } else {
      const float* hb = hin + (size_t)(node0 + l15)*Hn + (ks - 2)*32;
      const float4 f0 = *reinterpret_cast<const float4*>(hb + 4*g);
      const float4 f1 = *reinterpret_cast<const float4*>(hb + 16 + 4*g);
      hfv[ks-2][0] = f0.x; hfv[ks-2][1] = f0.y; hfv[ks-2][2] = f0.z; hfv[ks-2][3] = f0.w;
      hfv[ks-2][4] = f1.x; hfv[ks-2][5] = f1.y; hfv[ks-2][6] = f1.z; hfv[ks-2][7] = f1.w;
      split8(f0, f1, ah, al);
    }
    #pragma unroll
    for (int nt = 0; nt < 8; ++nt) {
      const int tile = 32 + ks*8 + nt;
      const bf16x8 bh = asbf(wB[(tile*2 + 0)*64 + lane]);
      const bf16x8 bl = asbf(wB[(tile*2 + 1)*64 + lane]);
      gg[nt] = mm(ah, bh, gg[nt]);
      gg[nt] = mm(ah, bl, gg[nt]);
      gg[nt] = mm(al, bh, gg[nt]);
    }
  }
  // sigmoid; r -> LDS (reuse e=1 slice); u in place
  float* rL = &sls[wid][1][0][0];
  #pragma unroll
  for (int nt = 0; nt < 4; ++nt)
    #pragma unroll
    for (int j = 0; j < 4; ++j) {
      const int m = 4*g + j;
      const float rr = 1.f / (1.f + __expf(-gg[nt][j]));
      rL[m*Hn + swzw(m, nt*16 + l15)] = rr;
      gg[4 + nt][j] = 1.f / (1.f + __expf(-gg[4 + nt][j]));
    }

  // ---- candidate via MFMA: cacc = [acts, r*h] @ Wc + bc
  f32x4 cacc[4];
  #pragma unroll
  for (int nt = 0; nt < 4; ++nt) {
    const float bcv = bc[nt*16 + l15];
    cacc[nt] = (f32x4){bcv, bcv, bcv, bcv};
  }
  #pragma unroll
  for (int ks = 0; ks < 4; ++ks) {
    bf16x8 ah, al;
    if (ks < 2) { ah = aah[ks]; al = aal[ks]; }
    else {
      const float4* rp = reinterpret_cast<const float4*>(&rL[l15*Hn]);
      const float4 f0 = rp[((ks - 2)*8 + g) ^ l15];
      const float4 f1 = rp[((ks - 2)*8 + 4 + g) ^ l15];
      float4 p0, p1;
      p0.x = f0.x * hfv[ks-2][0]; p0.y = f0.y * hfv[ks-2][1];
      p0.z = f0.z * hfv[ks-2][2]; p0.w = f0.w * hfv[ks-2][3];
      p1.x = f1.x * hfv[ks-2][4]; p1.y = f1.y * hfv[ks-2][5];
      p1.z = f1.z * hfv[ks-2][6]; p1.w = f1.w * hfv[ks-2][7];
      split8(p0, p1, ah, al);
    }
    #pragma unroll
    for (int nt = 0; nt < 4; ++nt) {
      const int tile = 64 + ks*4 + nt;
      const bf16x8 bh = asbf(wB[(tile*2 + 0)*64 + lane]);
      const bf16x8 bl = asbf(wB[(tile*2 + 1)*64 + lane]);
      cacc[nt] = mm(ah, bh, cacc[nt]);
      cacc[nt] = mm(ah, bl, cacc[nt]);
      cacc[nt] = mm(al, bh, cacc[nt]);
    }
  }

  // ---- final combine: h' = u*h + (1-u)*tanh(cacc) at (node 4g+j, d nt*16+l15)
  #pragma unroll
  for (int nt = 0; nt < 4; ++nt)
    #pragma unroll
    for (int j = 0; j < 4; ++j) {
      const int m = 4*g + j;
      float x = cacc[nt][j];
      x = fminf(fmaxf(x, -15.f), 15.f);
      const float ez = __expf(2.f * x);
      const float th = (ez - 1.f) / (ez + 1.f);
      const float uu = gg[4 + nt][j];
      const size_t off = (size_t)(node0 + m)*Hn + nt*16 + l15;
      hout[off] = uu * hin[off] + (1.f - uu) * th;
    }
}

// ---------------------------------------------------------------------------
extern "C" void kernel_launch(void* const* d_in, const int* in_sizes, int n_in,
                              void* d_out, int out_size, void* d_ws, size_t ws_size,
                              hipStream_t stream)
{
  const float* h0  = (const float*)d_in[0];
  const float* adj = (const float*)d_in[1];
  const float* We  = (const float*)d_in[2];
  const float* be  = (const float*)d_in[3];
  const float* Wg  = (const float*)d_in[4];
  const float* bg  = (const float*)d_in[5];
  const float* Wc  = (const float*)d_in[6];
  const float* bc  = (const float*)d_in[7];
  float* out = (float*)d_out;

  char* ws = (char*)d_ws;
  int*  idx = (int*)ws;  ws += (size_t)NROWS * CAP * sizeof(int);           // 12.6 MB
  int*  cnt = (int*)ws;  ws += (size_t)NROWS * sizeof(int);                 // 0.2 MB
  int4* wB  = (int4*)ws; ws += (size_t)80 * 2 * 64 * sizeof(int4);          // 160 KB
  float* hA = (float*)ws; ws += (size_t)(PADROW + 1) * Hn * sizeof(float);  // 3.15 MB
  float* hB = (float*)ws;                                                    // 3.15 MB

  sparsify_kernel<<<NROWS / 4, 256, 0, stream>>>(adj, idx, cnt);

  const int NH4 = Bn * Vn * Hn / 4;
  const int prep_threads = NH4 + 32 + 80 * 64;
  prep_kernel<<<(prep_threads + 255) / 256, 256, 0, stream>>>(h0, We, Wg, Wc, hA, hB, wB);

  const int blocks = Bn * Vn / (NT * 4);   // 192 blocks x 4 waves x 16 nodes
  const float* hin = hA;
  for (int t = 0; t < Tn; ++t) {
    float* ho = (t == Tn - 1) ? out : ((t & 1) ? hA : hB);
    step_kernel<<<blocks, 256, 0, stream>>>(hin, ho, idx, cnt, wB, be, bg, bc);
    hin = ho;
  }
}

// Round 10
// 251.286 us; speedup vs baseline: 1.5650x; 1.5650x over previous
//
#include <hip/hip_runtime.h>
#include <cstddef>

// GGNN: B=8, V=1536, H=64, E=4, T=5 (constants from setup_inputs()).
constexpr int Bn = 8, Vn = 1536, Hn = 64, En = 4, Tn = 5;
constexpr int CAP = 64;              // max nnz per adjacency row (mean 15.4, >12 sigma)
constexpr int NROWS = Bn * En * Vn;  // 49152
constexpr int PADROW = Bn * Vn;      // 12288 -> zeroed pad row in hA/hB
constexpr int NT = 16;               // nodes per wave (MFMA M=16)

typedef float fx4 __attribute__((ext_vector_type(4)));
typedef float f32x4 __attribute__((ext_vector_type(4)));
typedef short bf16x8 __attribute__((ext_vector_type(8)));

__device__ __forceinline__ unsigned short f2bf(float x) {
  unsigned u = __float_as_uint(x);
  return (unsigned short)((u + 0x7fffu + ((u >> 16) & 1u)) >> 16);
}
__device__ __forceinline__ float bf2f(unsigned short h) {
  return __uint_as_float(((unsigned)h) << 16);
}

// ---------------------------------------------------------------------------
// Pass 1: compact binary adjacency [B,E,V,V] into padded GLOBAL index lists.
// ---------------------------------------------------------------------------
__global__ __launch_bounds__(256) void sparsify_kernel(
    const float* __restrict__ adj, int* __restrict__ idx, int* __restrict__ cnt)
{
  __shared__ int lcnt[4];
  __shared__ int sidx[4][CAP];
  const int wid = threadIdx.x >> 6, lane = threadIdx.x & 63;
  const int row = blockIdx.x * 4 + wid;
  if (lane == 0) lcnt[wid] = 0;
  __syncthreads();
  const int b = row / (En * Vn);
  const fx4* a4 = reinterpret_cast<const fx4*>(adj + (size_t)row * Vn);
  for (int i = lane; i < Vn / 4; i += 64) {
    fx4 v = __builtin_nontemporal_load(&a4[i]);
    int base = i * 4;
    if (v.x != 0.f) { int s = atomicAdd(&lcnt[wid], 1); if (s < CAP) sidx[wid][s] = base + 0; }
    if (v.y != 0.f) { int s = atomicAdd(&lcnt[wid], 1); if (s < CAP) sidx[wid][s] = base + 1; }
    if (v.z != 0.f) { int s = atomicAdd(&lcnt[wid], 1); if (s < CAP) sidx[wid][s] = base + 2; }
    if (v.w != 0.f) { int s = atomicAdd(&lcnt[wid], 1); if (s < CAP) sidx[wid][s] = base + 3; }
  }
  __syncthreads();
  const int n = min(lcnt[wid], CAP);
  idx[(size_t)row * CAP + lane] = (lane < n) ? (b * Vn + sidx[wid][lane]) : PADROW;
  if (lane == 0) cnt[row] = n;
}

// ---------------------------------------------------------------------------
// Prep: h0 -> hA (+ zero pads); pack all weights as split-bf16 MFMA B-tiles.
// (Layouts hardware-verified in R9: absmax 0.0156.)
// ---------------------------------------------------------------------------
__global__ __launch_bounds__(256) void prep_kernel(
    const float* __restrict__ h0, const float* __restrict__ We,
    const float* __restrict__ Wg, const float* __restrict__ Wc,
    float* __restrict__ hA, float* __restrict__ hB, int4* __restrict__ wB)
{
  const int tid = blockIdx.x * 256 + threadIdx.x;
  const int NH4 = Bn * Vn * Hn / 4;
  if (tid < NH4) reinterpret_cast<float4*>(hA)[tid] = reinterpret_cast<const float4*>(h0)[tid];
  const int p = tid - NH4;
  if (p >= 0 && p < 16)  reinterpret_cast<float4*>(hA + (size_t)PADROW * Hn)[p]      = float4{0.f,0.f,0.f,0.f};
  if (p >= 16 && p < 32) reinterpret_cast<float4*>(hB + (size_t)PADROW * Hn)[p - 16] = float4{0.f,0.f,0.f,0.f};
  const int pk = p - 32;
  if (pk >= 0 && pk < 80 * 64) {
    const int tile = pk >> 6, l = pk & 63;
    const int g = l >> 4, n15 = l & 15;
    float w[8];
    if (tile < 32) {
      const int e = tile >> 3, ks = (tile >> 2) & 1, nt = tile & 3;
      const int col = nt * 16 + n15;
      #pragma unroll
      for (int jj = 0; jj < 4; ++jj) {
        w[jj]     = We[e*Hn*Hn + (ks*32      + 4*g + jj)*Hn + col];
        w[4 + jj] = We[e*Hn*Hn + (ks*32 + 16 + 4*g + jj)*Hn + col];
      }
    } else if (tile < 64) {
      const int t2 = tile - 32, ks = t2 >> 3, nt = t2 & 7;
      const int col = nt * 16 + n15;
      #pragma unroll
      for (int jj = 0; jj < 4; ++jj) {
        w[jj]     = Wg[(ks*32      + 4*g + jj)*2*Hn + col];
        w[4 + jj] = Wg[(ks*32 + 16 + 4*g + jj)*2*Hn + col];
      }
    } else {
      const int t2 = tile - 64, ks = t2 >> 2, nt = t2 & 3;
      const int col = nt * 16 + n15;
      #pragma unroll
      for (int jj = 0; jj < 4; ++jj) {
        w[jj]     = Wc[(ks*32      + 4*g + jj)*Hn + col];
        w[4 + jj] = Wc[(ks*32 + 16 + 4*g + jj)*Hn + col];
      }
    }
    unsigned hi[4], lo[4];
    #pragma unroll
    for (int q = 0; q < 4; ++q) {
      unsigned short h0_ = f2bf(w[2*q]), h1_ = f2bf(w[2*q + 1]);
      hi[q] = (unsigned)h0_ | ((unsigned)h1_ << 16);
      unsigned short l0_ = f2bf(w[2*q] - bf2f(h0_)), l1_ = f2bf(w[2*q + 1] - bf2f(h1_));
      lo[q] = (unsigned)l0_ | ((unsigned)l1_ << 16);
    }
    wB[(tile*2 + 0)*64 + l] = int4{(int)hi[0], (int)hi[1], (int)hi[2], (int)hi[3]};
    wB[(tile*2 + 1)*64 + l] = int4{(int)lo[0], (int)lo[1], (int)lo[2], (int)lo[3]};
  }
}

// ---------------------------------------------------------------------------
__device__ __forceinline__ int sel4(const int4 w, const int j4) {
  int r = w.x;
  r = (j4 == 1) ? w.y : r;
  r = (j4 == 2) ? w.z : r;
  r = (j4 == 3) ? w.w : r;
  return r;
}

// ---------------------------------------------------------------------------
// Gather: one wave per (b,e,v) row (R6 structure, verified). lane = (j4
// neighbor-slot, d4 dim-quarter); independent loads; butterfly reduce;
// lanes with j4==0 write the 256B s row. 49152 waves -> latency hidden.
// ---------------------------------------------------------------------------
__global__ __launch_bounds__(256) void gather_kernel(
    const float* __restrict__ hin, const int* __restrict__ idx,
    const int* __restrict__ cnt, float* __restrict__ s)
{
  const int lane = threadIdx.x & 63;
  const int row  = __builtin_amdgcn_readfirstlane(blockIdx.x * 4 + (threadIdx.x >> 6));
  const int j4 = lane >> 4, d4 = lane & 15;
  const int cn = cnt[row];
  const int rounds = (cn + 3) >> 2;
  const int4* ip = reinterpret_cast<const int4*>(idx + (size_t)row * CAP);
  const float4* hp = reinterpret_cast<const float4*>(hin);
  float4 a{0.f, 0.f, 0.f, 0.f};
  for (int j = 0; j < rounds; ++j) {
    const int4 w = ip[j];                         // uniform -> s_load_dwordx4
    const unsigned n = sel4(w, j4);
    const float4 v = hp[n * 16u + d4];            // pad rows read zeros
    a.x += v.x; a.y += v.y; a.z += v.z; a.w += v.w;
  }
  a.x += __shfl_xor(a.x, 16); a.y += __shfl_xor(a.y, 16);
  a.z += __shfl_xor(a.z, 16); a.w += __shfl_xor(a.w, 16);
  a.x += __shfl_xor(a.x, 32); a.y += __shfl_xor(a.y, 32);
  a.z += __shfl_xor(a.z, 32); a.w += __shfl_xor(a.w, 32);
  if (j4 == 0) reinterpret_cast<float4*>(s)[(size_t)row * 16 + d4] = a;
}

// ---------------------------------------------------------------------------
__device__ __forceinline__ int swzw(int row, int w) {       // word swizzle: chunk ^ row
  return (((w >> 2) ^ (row & 15)) << 2) | (w & 3);
}
__device__ __forceinline__ bf16x8 asbf(int4 v) {
  union { int4 i; bf16x8 b; } u; u.i = v; return u.b;
}
__device__ __forceinline__ void split8(float4 f0, float4 f1, bf16x8& hi, bf16x8& lo) {
  float v[8] = {f0.x, f0.y, f0.z, f0.w, f1.x, f1.y, f1.z, f1.w};
  #pragma unroll
  for (int j = 0; j < 8; ++j) {
    unsigned short h = f2bf(v[j]);
    hi[j] = (short)h;
    lo[j] = (short)f2bf(v[j] - bf2f(h));
  }
}
__device__ __forceinline__ f32x4 mm(bf16x8 a, bf16x8 b, f32x4 c) {
  return __builtin_amdgcn_mfma_f32_16x16x32_bf16(a, b, c, 0, 0, 0);
}

// ---------------------------------------------------------------------------
// MFMA step (no gather): one wave = 16 nodes. A-fragments for s loaded
// DIRECTLY from sbuf in fragment layout (4-lane groups hit full 64B lines,
// L2-hot). acts / r repacks via 8KB swizzled per-block LDS. Split-bf16 MFMA.
// ---------------------------------------------------------------------------
__global__ __launch_bounds__(64) void mstep_kernel(
    const float* __restrict__ hin, float* __restrict__ hout,
    const float* __restrict__ sbuf, const int* __restrict__ cnt,
    const int4* __restrict__ wB, const float* __restrict__ be,
    const float* __restrict__ bg, const float* __restrict__ bc)
{
  __shared__ float sls[2][NT][Hn];   // 8KB: [0]=acts, [1]=r
  const int lane = threadIdx.x;
  const int g = lane >> 4, l15 = lane & 15;
  const int node0 = __builtin_amdgcn_readfirstlane(blockIdx.x * NT);
  const int b = node0 / Vn, v0 = node0 - b * Vn;
  const int rbase = b * En * Vn + v0;

  // ---- acts bias: sum_e cnt_e * be[e]  (D-layout: row 4g+j, col nt*16+l15)
  f32x4 acc[4];
  {
    float cv[4][4];
    #pragma unroll
    for (int e = 0; e < 4; ++e)
      #pragma unroll
      for (int j = 0; j < 4; ++j)
        cv[e][j] = (float)cnt[rbase + e*Vn + 4*g + j];
    #pragma unroll
    for (int nt = 0; nt < 4; ++nt) {
      float bev[4];
      #pragma unroll
      for (int e = 0; e < 4; ++e) bev[e] = be[e*Hn + nt*16 + l15];
      #pragma unroll
      for (int j = 0; j < 4; ++j)
        acc[nt][j] = cv[0][j]*bev[0] + cv[1][j]*bev[1] + cv[2][j]*bev[2] + cv[3][j]*bev[3];
    }
  }

  // ---- edge transform via MFMA: acts += sum_e s_e @ We[e]
  #pragma unroll
  for (int e = 0; e < 4; ++e) {
    const float* sp = sbuf + (size_t)(rbase + e*Vn + l15) * Hn;  // A row = node l15
    #pragma unroll
    for (int ks = 0; ks < 2; ++ks) {
      const float4 f0 = *reinterpret_cast<const float4*>(sp + ks*32 + 4*g);
      const float4 f1 = *reinterpret_cast<const float4*>(sp + ks*32 + 16 + 4*g);
      bf16x8 ah, al; split8(f0, f1, ah, al);
      #pragma unroll
      for (int nt = 0; nt < 4; ++nt) {
        const int tile = (e*2 + ks)*4 + nt;
        const bf16x8 bh = asbf(wB[(tile*2 + 0)*64 + lane]);
        const bf16x8 bl = asbf(wB[(tile*2 + 1)*64 + lane]);
        acc[nt] = mm(ah, bh, acc[nt]);
        acc[nt] = mm(ah, bl, acc[nt]);
        acc[nt] = mm(al, bh, acc[nt]);
      }
    }
  }

  // ---- repack acts (D-layout) -> LDS [node][k] swizzled
  float* actsL = &sls[0][0][0];
  #pragma unroll
  for (int nt = 0; nt < 4; ++nt)
    #pragma unroll
    for (int j = 0; j < 4; ++j) {
      const int m = 4*g + j;
      actsL[m*Hn + swzw(m, nt*16 + l15)] = acc[nt][j];
    }

  // ---- gates via MFMA: gg = [acts, h] @ Wg + bg
  f32x4 gg[8];
  #pragma unroll
  for (int nt = 0; nt < 8; ++nt) {
    const float bgv = bg[nt*16 + l15];
    gg[nt] = (f32x4){bgv, bgv, bgv, bgv};
  }
  bf16x8 aah[2], aal[2];        // acts A-frags kept for cand
  float  hfv[2][8];             // h fp32 kept for rh
  #pragma unroll
  for (int ks = 0; ks < 4; ++ks) {
    bf16x8 ah, al;
    if (ks < 2) {
      const float4* ap4 = reinterpret_cast<const float4*>(&actsL[l15*Hn]);
      const float4 f0 = ap4[(ks*8 + g) ^ l15];
      const float4 f1 = ap4[(ks*8 + 4 + g) ^ l15];
      split8(f0, f1, ah, al);
      aah[ks] = ah; aal[ks] = al;
    } else {
      const float* hb = hin + (size_t)(node0 + l15)*Hn + (ks - 2)*32;
      const float4 f0 = *reinterpret_cast<const float4*>(hb + 4*g);
      const float4 f1 = *reinterpret_cast<const float4*>(hb + 16 + 4*g);
      hfv[ks-2][0] = f0.x; hfv[ks-2][1] = f0.y; hfv[ks-2][2] = f0.z; hfv[ks-2][3] = f0.w;
      hfv[ks-2][4] = f1.x; hfv[ks-2][5] = f1.y; hfv[ks-2][6] = f1.z; hfv[ks-2][7] = f1.w;
      split8(f0, f1, ah, al);
    }
    #pragma unroll
    for (int nt = 0; nt < 8; ++nt) {
      const int tile = 32 + ks*8 + nt;
      const bf16x8 bh = asbf(wB[(tile*2 + 0)*64 + lane]);
      const bf16x8 bl = asbf(wB[(tile*2 + 1)*64 + lane]);
      gg[nt] = mm(ah, bh, gg[nt]);
      gg[nt] = mm(ah, bl, gg[nt]);
      gg[nt] = mm(al, bh, gg[nt]);
    }
  }
  // sigmoid; r -> LDS swizzled; u in place
  float* rL = &sls[1][0][0];
  #pragma unroll
  for (int nt = 0; nt < 4; ++nt)
    #pragma unroll
    for (int j = 0; j < 4; ++j) {
      const int m = 4*g + j;
      const float rr = 1.f / (1.f + __expf(-gg[nt][j]));
      rL[m*Hn + swzw(m, nt*16 + l15)] = rr;
      gg[4 + nt][j] = 1.f / (1.f + __expf(-gg[4 + nt][j]));
    }

  // ---- candidate via MFMA: cacc = [acts, r*h] @ Wc + bc
  f32x4 cacc[4];
  #pragma unroll
  for (int nt = 0; nt < 4; ++nt) {
    const float bcv = bc[nt*16 + l15];
    cacc[nt] = (f32x4){bcv, bcv, bcv, bcv};
  }
  #pragma unroll
  for (int ks = 0; ks < 4; ++ks) {
    bf16x8 ah, al;
    if (ks < 2) { ah = aah[ks]; al = aal[ks]; }
    else {
      const float4* rp = reinterpret_cast<const float4*>(&rL[l15*Hn]);
      const float4 f0 = rp[((ks - 2)*8 + g) ^ l15];
      const float4 f1 = rp[((ks - 2)*8 + 4 + g) ^ l15];
      float4 p0, p1;
      p0.x = f0.x * hfv[ks-2][0]; p0.y = f0.y * hfv[ks-2][1];
      p0.z = f0.z * hfv[ks-2][2]; p0.w = f0.w * hfv[ks-2][3];
      p1.x = f1.x * hfv[ks-2][4]; p1.y = f1.y * hfv[ks-2][5];
      p1.z = f1.z * hfv[ks-2][6]; p1.w = f1.w * hfv[ks-2][7];
      split8(p0, p1, ah, al);
    }
    #pragma unroll
    for (int nt = 0; nt < 4; ++nt) {
      const int tile = 64 + ks*4 + nt;
      const bf16x8 bh = asbf(wB[(tile*2 + 0)*64 + lane]);
      const bf16x8 bl = asbf(wB[(tile*2 + 1)*64 + lane]);
      cacc[nt] = mm(ah, bh, cacc[nt]);
      cacc[nt] = mm(ah, bl, cacc[nt]);
      cacc[nt] = mm(al, bh, cacc[nt]);
    }
  }

  // ---- final combine: h' = u*h + (1-u)*tanh(cacc)
  #pragma unroll
  for (int nt = 0; nt < 4; ++nt)
    #pragma unroll
    for (int j = 0; j < 4; ++j) {
      const int m = 4*g + j;
      float x = cacc[nt][j];
      x = fminf(fmaxf(x, -15.f), 15.f);
      const float ez = __expf(2.f * x);
      const float th = (ez - 1.f) / (ez + 1.f);
      const float uu = gg[4 + nt][j];
      const size_t off = (size_t)(node0 + m)*Hn + nt*16 + l15;
      hout[off] = uu * hin[off] + (1.f - uu) * th;
    }
}

// ---------------------------------------------------------------------------
extern "C" void kernel_launch(void* const* d_in, const int* in_sizes, int n_in,
                              void* d_out, int out_size, void* d_ws, size_t ws_size,
                              hipStream_t stream)
{
  const float* h0  = (const float*)d_in[0];
  const float* adj = (const float*)d_in[1];
  const float* We  = (const float*)d_in[2];
  const float* be  = (const float*)d_in[3];
  const float* Wg  = (const float*)d_in[4];
  const float* bg  = (const float*)d_in[5];
  const float* Wc  = (const float*)d_in[6];
  const float* bc  = (const float*)d_in[7];
  float* out = (float*)d_out;

  char* ws = (char*)d_ws;
  int*   idx  = (int*)ws;   ws += (size_t)NROWS * CAP * sizeof(int);          // 12.6 MB
  int*   cnt  = (int*)ws;   ws += (size_t)NROWS * sizeof(int);                // 0.2 MB
  int4*  wB   = (int4*)ws;  ws += (size_t)80 * 2 * 64 * sizeof(int4);         // 160 KB
  float* sbuf = (float*)ws; ws += (size_t)NROWS * Hn * sizeof(float);         // 12.6 MB
  float* hA   = (float*)ws; ws += (size_t)(PADROW + 1) * Hn * sizeof(float);  // 3.15 MB
  float* hB   = (float*)ws;                                                    // 3.15 MB

  sparsify_kernel<<<NROWS / 4, 256, 0, stream>>>(adj, idx, cnt);

  const int NH4 = Bn * Vn * Hn / 4;
  const int prep_threads = NH4 + 32 + 80 * 64;
  prep_kernel<<<(prep_threads + 255) / 256, 256, 0, stream>>>(h0, We, Wg, Wc, hA, hB, wB);

  const float* hin = hA;
  for (int t = 0; t < Tn; ++t) {
    float* ho = (t == Tn - 1) ? out : ((t & 1) ? hA : hB);
    gather_kernel<<<NROWS / 4, 256, 0, stream>>>(hin, idx, cnt, sbuf);
    mstep_kernel<<<Bn * Vn / NT, 64, 0, stream>>>(hin, ho, sbuf, cnt, wB, be, bg, bc);
    hin = ho;
  }
}

// Round 11
// 227.583 us; speedup vs baseline: 1.7280x; 1.1042x over previous
//
#include <hip/hip_runtime.h>
#include <cstddef>

// GGNN: B=8, V=1536, H=64, E=4, T=5 (constants from setup_inputs()).
constexpr int Bn = 8, Vn = 1536, Hn = 64, En = 4, Tn = 5;
constexpr int CAP = 64;              // max nnz per adjacency row (mean 15.4, >12 sigma)
constexpr int NROWS = Bn * En * Vn;  // 49152
constexpr int PADROW = Bn * Vn;      // 12288 -> zeroed pad row in hA/hB

typedef float fx4 __attribute__((ext_vector_type(4)));
typedef float f32x4 __attribute__((ext_vector_type(4)));
typedef short bf16x8 __attribute__((ext_vector_type(8)));

__device__ __forceinline__ unsigned short f2bf(float x) {
  unsigned u = __float_as_uint(x);
  return (unsigned short)((u + 0x7fffu + ((u >> 16) & 1u)) >> 16);
}
__device__ __forceinline__ float bf2f(unsigned short h) {
  return __uint_as_float(((unsigned)h) << 16);
}

// ---------------------------------------------------------------------------
// Pass 1: compact binary adjacency [B,E,V,V] into padded GLOBAL index lists.
// ---------------------------------------------------------------------------
__global__ __launch_bounds__(256) void sparsify_kernel(
    const float* __restrict__ adj, int* __restrict__ idx, int* __restrict__ cnt)
{
  __shared__ int lcnt[4];
  __shared__ int sidx[4][CAP];
  const int wid = threadIdx.x >> 6, lane = threadIdx.x & 63;
  const int row = blockIdx.x * 4 + wid;
  if (lane == 0) lcnt[wid] = 0;
  __syncthreads();
  const int b = row / (En * Vn);
  const fx4* a4 = reinterpret_cast<const fx4*>(adj + (size_t)row * Vn);
  for (int i = lane; i < Vn / 4; i += 64) {
    fx4 v = __builtin_nontemporal_load(&a4[i]);
    int base = i * 4;
    if (v.x != 0.f) { int s = atomicAdd(&lcnt[wid], 1); if (s < CAP) sidx[wid][s] = base + 0; }
    if (v.y != 0.f) { int s = atomicAdd(&lcnt[wid], 1); if (s < CAP) sidx[wid][s] = base + 1; }
    if (v.z != 0.f) { int s = atomicAdd(&lcnt[wid], 1); if (s < CAP) sidx[wid][s] = base + 2; }
    if (v.w != 0.f) { int s = atomicAdd(&lcnt[wid], 1); if (s < CAP) sidx[wid][s] = base + 3; }
  }
  __syncthreads();
  const int n = min(lcnt[wid], CAP);
  idx[(size_t)row * CAP + lane] = (lane < n) ? (b * Vn + sidx[wid][lane]) : PADROW;
  if (lane == 0) cnt[row] = n;
}

// ---------------------------------------------------------------------------
// Prep: h0 -> hA (+ zero pads); pack all weights as split-bf16 MFMA B-tiles.
// (Layouts hardware-verified in R9/R10: absmax 0.0156.)
// ---------------------------------------------------------------------------
__global__ __launch_bounds__(256) void prep_kernel(
    const float* __restrict__ h0, const float* __restrict__ We,
    const float* __restrict__ Wg, const float* __restrict__ Wc,
    float* __restrict__ hA, float* __restrict__ hB, int4* __restrict__ wB)
{
  const int tid = blockIdx.x * 256 + threadIdx.x;
  const int NH4 = Bn * Vn * Hn / 4;
  if (tid < NH4) reinterpret_cast<float4*>(hA)[tid] = reinterpret_cast<const float4*>(h0)[tid];
  const int p = tid - NH4;
  if (p >= 0 && p < 16)  reinterpret_cast<float4*>(hA + (size_t)PADROW * Hn)[p]      = float4{0.f,0.f,0.f,0.f};
  if (p >= 16 && p < 32) reinterpret_cast<float4*>(hB + (size_t)PADROW * Hn)[p - 16] = float4{0.f,0.f,0.f,0.f};
  const int pk = p - 32;
  if (pk >= 0 && pk < 80 * 64) {
    const int tile = pk >> 6, l = pk & 63;
    const int g = l >> 4, n15 = l & 15;
    float w[8];
    if (tile < 32) {
      const int e = tile >> 3, ks = (tile >> 2) & 1, nt = tile & 3;
      const int col = nt * 16 + n15;
      #pragma unroll
      for (int jj = 0; jj < 4; ++jj) {
        w[jj]     = We[e*Hn*Hn + (ks*32      + 4*g + jj)*Hn + col];
        w[4 + jj] = We[e*Hn*Hn + (ks*32 + 16 + 4*g + jj)*Hn + col];
      }
    } else if (tile < 64) {
      const int t2 = tile - 32, ks = t2 >> 3, nt = t2 & 7;
      const int col = nt * 16 + n15;
      #pragma unroll
      for (int jj = 0; jj < 4; ++jj) {
        w[jj]     = Wg[(ks*32      + 4*g + jj)*2*Hn + col];
        w[4 + jj] = Wg[(ks*32 + 16 + 4*g + jj)*2*Hn + col];
      }
    } else {
      const int t2 = tile - 64, ks = t2 >> 2, nt = t2 & 3;
      const int col = nt * 16 + n15;
      #pragma unroll
      for (int jj = 0; jj < 4; ++jj) {
        w[jj]     = Wc[(ks*32      + 4*g + jj)*Hn + col];
        w[4 + jj] = Wc[(ks*32 + 16 + 4*g + jj)*Hn + col];
      }
    }
    unsigned hi[4], lo[4];
    #pragma unroll
    for (int q = 0; q < 4; ++q) {
      unsigned short h0_ = f2bf(w[2*q]), h1_ = f2bf(w[2*q + 1]);
      hi[q] = (unsigned)h0_ | ((unsigned)h1_ << 16);
      unsigned short l0_ = f2bf(w[2*q] - bf2f(h0_)), l1_ = f2bf(w[2*q + 1] - bf2f(h1_));
      lo[q] = (unsigned)l0_ | ((unsigned)l1_ << 16);
    }
    wB[(tile*2 + 0)*64 + l] = int4{(int)hi[0], (int)hi[1], (int)hi[2], (int)hi[3]};
    wB[(tile*2 + 1)*64 + l] = int4{(int)lo[0], (int)lo[1], (int)lo[2], (int)lo[3]};
  }
}

// ---------------------------------------------------------------------------
__device__ __forceinline__ int sel4(const int4 w, const int j4) {
  int r = w.x;
  r = (j4 == 1) ? w.y : r;
  r = (j4 == 2) ? w.z : r;
  r = (j4 == 3) ? w.w : r;
  return r;
}

// ---------------------------------------------------------------------------
// Gather: one wave per (b,e,v) row (verified R6/R10). 49152 waves, 8/SIMD.
// ---------------------------------------------------------------------------
__global__ __launch_bounds__(256) void gather_kernel(
    const float* __restrict__ hin, const int* __restrict__ idx,
    const int* __restrict__ cnt, float* __restrict__ s)
{
  const int lane = threadIdx.x & 63;
  const int row  = __builtin_amdgcn_readfirstlane(blockIdx.x * 4 + (threadIdx.x >> 6));
  const int j4 = lane >> 4, d4 = lane & 15;
  const int cn = cnt[row];
  const int rounds = (cn + 3) >> 2;
  const int4* ip = reinterpret_cast<const int4*>(idx + (size_t)row * CAP);
  const float4* hp = reinterpret_cast<const float4*>(hin);
  float4 a{0.f, 0.f, 0.f, 0.f};
  for (int j = 0; j < rounds; ++j) {
    const int4 w = ip[j];                         // uniform -> s_load_dwordx4
    const unsigned n = sel4(w, j4);
    const float4 v = hp[n * 16u + d4];            // pad rows read zeros
    a.x += v.x; a.y += v.y; a.z += v.z; a.w += v.w;
  }
  a.x += __shfl_xor(a.x, 16); a.y += __shfl_xor(a.y, 16);
  a.z += __shfl_xor(a.z, 16); a.w += __shfl_xor(a.w, 16);
  a.x += __shfl_xor(a.x, 32); a.y += __shfl_xor(a.y, 32);
  a.z += __shfl_xor(a.z, 32); a.w += __shfl_xor(a.w, 32);
  if (j4 == 0) reinterpret_cast<float4*>(s)[(size_t)row * 16 + d4] = a;
}

// ---------------------------------------------------------------------------
__device__ __forceinline__ int swzw(int row, int w) {       // word swizzle: chunk ^ row
  return (((w >> 2) ^ (row & 15)) << 2) | (w & 3);
}
__device__ __forceinline__ bf16x8 asbf(int4 v) {
  union { int4 i; bf16x8 b; } u; u.i = v; return u.b;
}
__device__ __forceinline__ void split8(float4 f0, float4 f1, bf16x8& hi, bf16x8& lo) {
  float v[8] = {f0.x, f0.y, f0.z, f0.w, f1.x, f1.y, f1.z, f1.w};
  #pragma unroll
  for (int j = 0; j < 8; ++j) {
    unsigned short h = f2bf(v[j]);
    hi[j] = (short)h;
    lo[j] = (short)f2bf(v[j] - bf2f(h));
  }
}
__device__ __forceinline__ f32x4 mm(bf16x8 a, bf16x8 b, f32x4 c) {
  return __builtin_amdgcn_mfma_f32_16x16x32_bf16(a, b, c, 0, 0, 0);
}

// ---------------------------------------------------------------------------
// MFMA step, column-split: block = 256 threads (4 waves) serving the SAME 16
// nodes; wave wid owns output tiles {edge nt=wid, gates nt=2wid..2wid+1,
// cand nt=wid}. acts / r*h / u exchanged via 12KB block LDS, 2 barriers.
// 768 blocks x 4 waves = 3072 waves (3/SIMD) -> weight-stream latency hidden.
// ---------------------------------------------------------------------------
__global__ __launch_bounds__(256) void mstep_kernel(
    const float* __restrict__ hin, float* __restrict__ hout,
    const float* __restrict__ sbuf, const int* __restrict__ cnt,
    const int4* __restrict__ wB, const float* __restrict__ be,
    const float* __restrict__ bg, const float* __restrict__ bc)
{
  __shared__ float actsL[16 * 64];   // swizzled [node][k]
  __shared__ float rhL[16 * 64];     // swizzled [node][k]
  __shared__ float uL[16][68];       // plain, padded
  const int lane = threadIdx.x & 63;
  const int wid  = threadIdx.x >> 6;
  const int g = lane >> 4, l15 = lane & 15;
  const int node0 = __builtin_amdgcn_readfirstlane(blockIdx.x * 16);
  const int b = node0 / Vn, v0 = node0 - b * Vn;
  const int rbase = b * En * Vn + v0;
  const int myc = wid * 16 + l15;          // own column (edge / cand / final)

  // ---- bias: acc[j] = sum_e cnt_e(node 4g+j) * be[e][myc]
  f32x4 acc;
  {
    float bev[4];
    #pragma unroll
    for (int e = 0; e < 4; ++e) bev[e] = be[e*Hn + myc];
    #pragma unroll
    for (int j = 0; j < 4; ++j) {
      float a = 0.f;
      #pragma unroll
      for (int e = 0; e < 4; ++e) a += (float)cnt[rbase + e*Vn + 4*g + j] * bev[e];
      acc[j] = a;
    }
  }

  // ---- edge transform (own nt = wid): acc += sum_e s_e @ We[e][:, myc-tile]
  #pragma unroll
  for (int e = 0; e < 4; ++e) {
    const float* sp = sbuf + (size_t)(rbase + e*Vn + l15) * Hn;   // A row = node l15
    #pragma unroll
    for (int ks = 0; ks < 2; ++ks) {
      const float4 f0 = *reinterpret_cast<const float4*>(sp + ks*32 + 4*g);
      const float4 f1 = *reinterpret_cast<const float4*>(sp + ks*32 + 16 + 4*g);
      bf16x8 ah, al; split8(f0, f1, ah, al);
      const int tile = (e*2 + ks)*4 + wid;
      const bf16x8 bh = asbf(wB[(tile*2 + 0)*64 + lane]);
      const bf16x8 bl = asbf(wB[(tile*2 + 1)*64 + lane]);
      acc = mm(ah, bh, acc);
      acc = mm(ah, bl, acc);
      acc = mm(al, bh, acc);
    }
  }
  // write acts (D-layout row m=4g+j, col myc) -> swizzled LDS
  #pragma unroll
  for (int j = 0; j < 4; ++j) {
    const int m = 4*g + j;
    actsL[m*Hn + swzw(m, myc)] = acc[j];
  }
  __syncthreads();

  // ---- gates (own nt = 2wid, 2wid+1): gg = [acts, h] @ Wg + bg
  f32x4 gg0, gg1;
  {
    const float b0 = bg[(2*wid)*16 + l15], b1 = bg[(2*wid + 1)*16 + l15];
    gg0 = (f32x4){b0, b0, b0, b0};
    gg1 = (f32x4){b1, b1, b1, b1};
  }
  bf16x8 aah[2], aal[2];                   // acts A-frags cached for cand
  #pragma unroll
  for (int ks = 0; ks < 4; ++ks) {
    bf16x8 ah, al;
    if (ks < 2) {
      const float4* ap4 = reinterpret_cast<const float4*>(actsL + l15*Hn);
      const float4 f0 = ap4[(ks*8 + g) ^ l15];
      const float4 f1 = ap4[(ks*8 + 4 + g) ^ l15];
      split8(f0, f1, ah, al);
      aah[ks] = ah; aal[ks] = al;
    } else {
      const float* hb = hin + (size_t)(node0 + l15)*Hn + (ks - 2)*32;
      const float4 f0 = *reinterpret_cast<const float4*>(hb + 4*g);
      const float4 f1 = *reinterpret_cast<const float4*>(hb + 16 + 4*g);
      split8(f0, f1, ah, al);
    }
    const int t0 = 32 + ks*8 + 2*wid;
    {
      const bf16x8 bh = asbf(wB[(t0*2 + 0)*64 + lane]);
      const bf16x8 bl = asbf(wB[(t0*2 + 1)*64 + lane]);
      gg0 = mm(ah, bh, gg0); gg0 = mm(ah, bl, gg0); gg0 = mm(al, bh, gg0);
    }
    {
      const bf16x8 bh = asbf(wB[((t0 + 1)*2 + 0)*64 + lane]);
      const bf16x8 bl = asbf(wB[((t0 + 1)*2 + 1)*64 + lane]);
      gg1 = mm(ah, bh, gg1); gg1 = mm(ah, bl, gg1); gg1 = mm(al, bh, gg1);
    }
  }
  // sigmoid + exchange: waves 0,1 produce r (cols 0..63) -> rhL; waves 2,3 u -> uL
  if (wid < 2) {
    #pragma unroll
    for (int t = 0; t < 2; ++t) {
      const int col = (2*wid + t)*16 + l15;
      const f32x4 G = t ? gg1 : gg0;
      #pragma unroll
      for (int j = 0; j < 4; ++j) {
        const int m = 4*g + j;
        const float r = 1.f / (1.f + __expf(-G[j]));
        rhL[m*Hn + swzw(m, col)] = r * hin[(size_t)(node0 + m)*Hn + col];
      }
    }
  } else {
    #pragma unroll
    for (int t = 0; t < 2; ++t) {
      const int col = (2*(wid - 2) + t)*16 + l15;
      const f32x4 G = t ? gg1 : gg0;
      #pragma unroll
      for (int j = 0; j < 4; ++j)
        uL[4*g + j][col] = 1.f / (1.f + __expf(-G[j]));
    }
  }
  __syncthreads();

  // ---- candidate (own nt = wid): cacc = [acts, r*h] @ Wc + bc
  f32x4 cacc;
  {
    const float bcl = bc[myc];
    cacc = (f32x4){bcl, bcl, bcl, bcl};
  }
  #pragma unroll
  for (int ks = 0; ks < 4; ++ks) {
    bf16x8 ah, al;
    if (ks < 2) { ah = aah[ks]; al = aal[ks]; }
    else {
      const float4* rp4 = reinterpret_cast<const float4*>(rhL + l15*Hn);
      const float4 f0 = rp4[((ks - 2)*8 + g) ^ l15];
      const float4 f1 = rp4[((ks - 2)*8 + 4 + g) ^ l15];
      split8(f0, f1, ah, al);
    }
    const int tile = 64 + ks*4 + wid;
    const bf16x8 bh = asbf(wB[(tile*2 + 0)*64 + lane]);
    const bf16x8 bl = asbf(wB[(tile*2 + 1)*64 + lane]);
    cacc = mm(ah, bh, cacc);
    cacc = mm(ah, bl, cacc);
    cacc = mm(al, bh, cacc);
  }

  // ---- final combine at (node 4g+j, col myc): h' = u*h + (1-u)*tanh(cacc)
  #pragma unroll
  for (int j = 0; j < 4; ++j) {
    const int m = 4*g + j;
    float x = fminf(fmaxf(cacc[j], -15.f), 15.f);
    const float ez = __expf(2.f * x);
    const float th = (ez - 1.f) / (ez + 1.f);
    const float uu = uL[m][myc];
    const size_t off = (size_t)(node0 + m)*Hn + myc;
    hout[off] = uu * hin[off] + (1.f - uu) * th;
  }
}

// ---------------------------------------------------------------------------
extern "C" void kernel_launch(void* const* d_in, const int* in_sizes, int n_in,
                              void* d_out, int out_size, void* d_ws, size_t ws_size,
                              hipStream_t stream)
{
  const float* h0  = (const float*)d_in[0];
  const float* adj = (const float*)d_in[1];
  const float* We  = (const float*)d_in[2];
  const float* be  = (const float*)d_in[3];
  const float* Wg  = (const float*)d_in[4];
  const float* bg  = (const float*)d_in[5];
  const float* Wc  = (const float*)d_in[6];
  const float* bc  = (const float*)d_in[7];
  float* out = (float*)d_out;

  char* ws = (char*)d_ws;
  int*   idx  = (int*)ws;   ws += (size_t)NROWS * CAP * sizeof(int);          // 12.6 MB
  int*   cnt  = (int*)ws;   ws += (size_t)NROWS * sizeof(int);                // 0.2 MB
  int4*  wB   = (int4*)ws;  ws += (size_t)80 * 2 * 64 * sizeof(int4);         // 160 KB
  float* sbuf = (float*)ws; ws += (size_t)NROWS * Hn * sizeof(float);         // 12.6 MB
  float* hA   = (float*)ws; ws += (size_t)(PADROW + 1) * Hn * sizeof(float);  // 3.15 MB
  float* hB   = (float*)ws;                                                    // 3.15 MB

  sparsify_kernel<<<NROWS / 4, 256, 0, stream>>>(adj, idx, cnt);

  const int NH4 = Bn * Vn * Hn / 4;
  const int prep_threads = NH4 + 32 + 80 * 64;
  prep_kernel<<<(prep_threads + 255) / 256, 256, 0, stream>>>(h0, We, Wg, Wc, hA, hB, wB);

  const float* hin = hA;
  for (int t = 0; t < Tn; ++t) {
    float* ho = (t == Tn - 1) ? out : ((t & 1) ? hA : hB);
    gather_kernel<<<NROWS / 4, 256, 0, stream>>>(hin, idx, cnt, sbuf);
    mstep_kernel<<<Bn * Vn / 16, 256, 0, stream>>>(hin, ho, sbuf, cnt, wB, be, bg, bc);
    hin = ho;
  }
}